// Round 4
// baseline (1091.828 us; speedup 1.0000x reference)
//
#include <hip/hip_runtime.h>

#define S_LEN 1024
#define D_DIM 64
#define QB 16
#define NTHREADS 1024
#define LSTR 1036      // f32 per logits row (1024 + 12 pad) = 4144 B
#define ESTR 2072      // u16 per row (same 4144 B rows)
#define ELO 1024       // u16 col offset of E-lo half within a row
#define RINV_OFF 66304 // 16 * 4144
#define LDS_BYTES 66368

#define NBH 128
#define KV_ELEMS ((size_t)NBH * S_LEN * D_DIM)   // 8388608
#define WS_NEED (KV_ELEMS * 8)                   // 4 u16 planes = 67108864 B

typedef short s16x8 __attribute__((ext_vector_type(8)));
typedef short s16x4 __attribute__((ext_vector_type(4)));
typedef float f32x4 __attribute__((ext_vector_type(4)));
typedef unsigned short u16;
typedef unsigned int u32;

static __device__ __forceinline__ u16 f2bf_rne(float f) {
  u32 u = __builtin_bit_cast(u32, f);
  return (u16)((u + 0x7fffu + ((u >> 16) & 1u)) >> 16);
}

// fp32 -> bf16 hi (trunc) + bf16 lo (RNE of remainder); hi+lo ~ 2^-17 rel err
static __device__ __forceinline__ void split2(float f, u16& h, u16& l) {
  u32 u = __builtin_bit_cast(u32, f);
  h = (u16)(u >> 16);
  float hf = __builtin_bit_cast(float, u & 0xffff0000u);
  l = f2bf_rne(f - hf);
}

static __device__ __forceinline__ f32x4 mfma16(s16x8 a, s16x8 b, f32x4 c) {
  return __builtin_amdgcn_mfma_f32_16x16x32_bf16(a, b, c, 0, 0, 0);
}

static __device__ __forceinline__ void cvt8(f32x4 a, f32x4 b, s16x8& h, s16x8& l) {
  s16x8 hh, ll;
#pragma unroll
  for (int j = 0; j < 8; ++j) {
    float fj = (j < 4) ? a[j] : b[j - 4];
    u16 hb, lb;
    split2(fj, hb, lb);
    hh[j] = (short)hb;
    ll[j] = (short)lb;
  }
  h = hh; l = ll;
}

// ---- precompute: K -> hi/lo bf16 planes, row-major [bh][t][d] ----
extern "C" __global__ void __launch_bounds__(256)
presplit_k(const float* __restrict__ kg, u16* __restrict__ khi, u16* __restrict__ klo) {
  const size_t base = ((size_t)blockIdx.x * 256 + threadIdx.x) * 8;
  f32x4 a = __builtin_nontemporal_load((const f32x4*)(kg + base));
  f32x4 b = __builtin_nontemporal_load((const f32x4*)(kg + base + 4));
  s16x8 h, l;
  cvt8(a, b, h, l);
  *(s16x8*)(khi + base) = h;
  *(s16x8*)(klo + base) = l;
}

// ---- precompute: V -> transposed hi/lo bf16 planes [bh][d][t] ----
extern "C" __global__ void __launch_bounds__(256)
presplit_vt(const float* __restrict__ vg, u16* __restrict__ vthi, u16* __restrict__ vtlo) {
  __shared__ u16 ht[64][72];   // [d][tt], stride 72 u16 = 144 B (bank-safe)
  __shared__ u16 lt[64][72];
  const int tid = threadIdx.x;
  const int bh = blockIdx.x >> 4;
  const int t0 = (blockIdx.x & 15) * 64;
  const float* vp = vg + ((size_t)bh * S_LEN + t0) * D_DIM;
#pragma unroll
  for (int it = 0; it < 16; ++it) {
    const int idx = it * 256 + tid;        // tt = idx>>6, d = idx&63 (coalesced)
    float f = __builtin_nontemporal_load(vp + idx);
    u16 h, l;
    split2(f, h, l);
    ht[idx & 63][idx >> 6] = h;
    lt[idx & 63][idx >> 6] = l;
  }
  __syncthreads();
#pragma unroll
  for (int o = tid; o < 2048; o += 256) {  // u32-packed write-out, coalesced
    const int d = o >> 5;
    const int tp = (o & 31) * 2;
    u32 wh = (u32)ht[d][tp] | ((u32)ht[d][tp + 1] << 16);
    u32 wl = (u32)lt[d][tp] | ((u32)lt[d][tp + 1] << 16);
    const size_t off = ((size_t)bh * D_DIM + d) * S_LEN + t0 + tp;
    *(u32*)(vthi + off) = wh;
    *(u32*)(vtlo + off) = wl;
  }
}

template <bool PRE>
__global__ __launch_bounds__(NTHREADS, 8) void
attn_fused(const float* __restrict__ qg, const float* __restrict__ kg,
           const float* __restrict__ vg, const float* __restrict__ mg,
           float* __restrict__ og, float* __restrict__ wg,
           const u16* __restrict__ khi, const u16* __restrict__ klo,
           const u16* __restrict__ vthi, const u16* __restrict__ vtlo)
{
  extern __shared__ char smem[];
  float* L = (float*)smem;            // [16][LSTR] f32 logits
  u16* E = (u16*)smem;                // row overlay: E-hi cols 0..1023, E-lo at +ELO
  float* sc = (float*)smem;           // 16 KB scratch overlay (after phase-3 barrier)
  float* rinv = (float*)(smem + RINV_OFF);

  const int tid = threadIdx.x;
  const int wave = tid >> 6;          // 0..15
  const int lane = tid & 63;
  const int l15 = lane & 15;
  const int lg4 = lane >> 4;

  // XCD-aware swizzle (bijective): XCD x runs bh in [16x,16x+16), qb-major
  const int bid = (int)blockIdx.x;
  const int swz = (bid & 7) * 1024 + (bid >> 3);
  const int qb = swz & 63;
  const int bh = swz >> 6;
  const int qbase = qb * QB;

  const float* qp = qg + (size_t)bh * S_LEN * D_DIM;

  // ===== Phase 1: L[s][t] = (q/8)·k + mask_padded * -1e9  (f32 in LDS) =====
  // A-frag: row=lane&15 (q), k=(lane>>4)*8+ks*32+i ; B-frag: col=lane&15 (t), same k.
  // C/D: col=lane&15 (t), row=(lane>>4)*4+j (q).   [verified rounds 1-3]
  {
    s16x8 qh[2], ql[2];
    const float* qrow = qp + (size_t)(qbase + l15) * D_DIM + lg4 * 8;
#pragma unroll
    for (int ks = 0; ks < 2; ++ks) {
      f32x4 a = *(const f32x4*)(qrow + ks * 32);
      f32x4 b = *(const f32x4*)(qrow + ks * 32 + 4);
#pragma unroll
      for (int j = 0; j < 4; ++j) { a[j] *= 0.125f; b[j] *= 0.125f; }  // fold 1/sqrt(64)
      cvt8(a, b, qh[ks], ql[ks]);
    }

#pragma unroll 2
    for (int ct = 0; ct < 4; ++ct) {
      const int t = wave * 64 + ct * 16 + l15;     // 16 waves cover 1024 t
      s16x8 kh[2], kl[2];
      if constexpr (PRE) {
        const u16* kb = khi + ((size_t)bh * S_LEN + t) * D_DIM + lg4 * 8;
        const u16* lb = klo + ((size_t)bh * S_LEN + t) * D_DIM + lg4 * 8;
#pragma unroll
        for (int ks = 0; ks < 2; ++ks) {
          kh[ks] = *(const s16x8*)(kb + ks * 32);
          kl[ks] = *(const s16x8*)(lb + ks * 32);
        }
      } else {
        const float* krow = kg + ((size_t)bh * S_LEN + t) * D_DIM + lg4 * 8;
#pragma unroll
        for (int ks = 0; ks < 2; ++ks) {
          f32x4 a = *(const f32x4*)(krow + ks * 32);
          f32x4 b = *(const f32x4*)(krow + ks * 32 + 4);
          cvt8(a, b, kh[ks], kl[ks]);
        }
      }
      f32x4 acc = {0.f, 0.f, 0.f, 0.f};
#pragma unroll
      for (int ks = 0; ks < 2; ++ks) {
        acc = mfma16(qh[ks], kh[ks], acc);
        acc = mfma16(qh[ks], kl[ks], acc);
        acc = mfma16(ql[ks], kh[ks], acc);
      }
#pragma unroll
      for (int j = 0; j < 4; ++j) {
        const int rl = lg4 * 4 + j;
        const int s = qbase + rl;
        float mv = 0.f;
        if (s > 0 && t > 0) mv = mg[(size_t)(s - 1) * (S_LEN - 1) + (t - 1)];
        L[rl * LSTR + t] = fmaf(mv, -1.0e9f, acc[j]);
      }
    }
  }
  __syncthreads();

  // ===== Phase 2: one wave per row; softmax; weights -> global (nt); E hi/lo in place =====
  {
    const float* Lr = L + wave * LSTR;
    f32x4 lv[4];
#pragma unroll
    for (int g = 0; g < 4; ++g) lv[g] = *(const f32x4*)&Lr[lane * 4 + g * 256];
    float m = -3.402823466e38f;
#pragma unroll
    for (int g = 0; g < 4; ++g)
#pragma unroll
      for (int j = 0; j < 4; ++j) m = fmaxf(m, lv[g][j]);
#pragma unroll
    for (int off = 1; off < 64; off <<= 1) m = fmaxf(m, __shfl_xor(m, off, 64));

    float sum = 0.f;
#pragma unroll
    for (int g = 0; g < 4; ++g)
#pragma unroll
      for (int j = 0; j < 4; ++j) {
        float ex = __expf(lv[g][j] - m);
        lv[g][j] = ex;
        sum += ex;
      }
#pragma unroll
    for (int off = 1; off < 64; off <<= 1) sum += __shfl_xor(sum, off, 64);
    const float inv = 1.0f / sum;
    if (lane == 0) rinv[wave] = inv;

    float* wrow = wg + (size_t)bh * S_LEN * S_LEN + (size_t)(qbase + wave) * S_LEN;
    u16* Er = E + wave * ESTR;
#pragma unroll
    for (int g = 0; g < 4; ++g) {
      const int col = lane * 4 + g * 256;
      f32x4 wv;
      s16x4 eh, el;
#pragma unroll
      for (int j = 0; j < 4; ++j) {
        wv[j] = lv[g][j] * inv;
        u16 hb, lb;
        split2(lv[g][j], hb, lb);
        eh[j] = (short)hb;
        el[j] = (short)lb;
      }
      __builtin_nontemporal_store(wv, (f32x4*)&wrow[col]);  // streaming: don't allocate L2
      *(s16x4*)&Er[col] = eh;              // in-row overlay (this wave owns the row)
      *(s16x4*)&Er[ELO + col] = el;
    }
  }
  __syncthreads();

  // ===== Phase 3: PV, barrier-free; V-frags straight from L2; split-K over t =====
  const int g3 = wave >> 2;               // t-range group 0..3
  const int ct = wave & 3;                // d-tile 0..3
  const int dcol = ct * 16 + l15;
  f32x4 acc = {0.f, 0.f, 0.f, 0.f};
#pragma unroll 2
  for (int T = g3 * 8; T < g3 * 8 + 8; ++T) {
    const int t0 = T * 32 + lg4 * 8;
    s16x8 vh, vl;
    if constexpr (PRE) {
      const size_t off = ((size_t)bh * D_DIM + dcol) * S_LEN + t0;
      vh = *(const s16x8*)(vthi + off);
      vl = *(const s16x8*)(vtlo + off);
    } else {
#pragma unroll
      for (int i = 0; i < 8; ++i) {
        u16 hb, lb;
        split2(vg[((size_t)bh * S_LEN + t0 + i) * D_DIM + dcol], hb, lb);
        vh[i] = (short)hb;
        vl[i] = (short)lb;
      }
    }
    s16x8 ah = *(const s16x8*)&E[l15 * ESTR + t0];
    s16x8 al = *(const s16x8*)&E[l15 * ESTR + ELO + t0];
    acc = mfma16(ah, vh, acc);
    acc = mfma16(ah, vl, acc);
    acc = mfma16(al, vh, acc);
  }
  __syncthreads();                        // all E reads done before scratch overlay

#pragma unroll
  for (int j = 0; j < 4; ++j)
    sc[g3 * 1024 + (lg4 * 4 + j) * 64 + dcol] = acc[j];
  __syncthreads();

  // reduce 4 split-K partials; scale by 1/sum; store output
  {
    const int q = wave;                   // 0..15
    const int d = lane;                   // 0..63
    float s = sc[q * 64 + d] + sc[1024 + q * 64 + d] +
              sc[2048 + q * 64 + d] + sc[3072 + q * 64 + d];
    __builtin_nontemporal_store(s * rinv[q],
        &og[(size_t)bh * S_LEN * D_DIM + (size_t)(qbase + q) * D_DIM + d]);
  }
}

extern "C" void kernel_launch(void* const* d_in, const int* in_sizes, int n_in,
                              void* d_out, int out_size, void* d_ws, size_t ws_size,
                              hipStream_t stream) {
  const float* q = (const float*)d_in[0];
  const float* k = (const float*)d_in[1];
  const float* v = (const float*)d_in[2];
  const float* m = (const float*)d_in[3];
  float* out = (float*)d_out;
  float* w = out + (size_t)8 * 16 * S_LEN * D_DIM;   // weights follow output (tuple order)

  u16* khi = (u16*)d_ws;
  u16* klo = khi + KV_ELEMS;
  u16* vthi = klo + KV_ELEMS;
  u16* vtlo = vthi + KV_ELEMS;

  if (ws_size >= WS_NEED) {
    presplit_k<<<dim3(4096), 256, 0, stream>>>(k, khi, klo);
    presplit_vt<<<dim3(2048), 256, 0, stream>>>(v, vthi, vtlo);
    hipFuncSetAttribute(reinterpret_cast<const void*>(attn_fused<true>),
                        hipFuncAttributeMaxDynamicSharedMemorySize, LDS_BYTES);
    attn_fused<true><<<dim3(8192), NTHREADS, LDS_BYTES, stream>>>(
        q, k, v, m, out, w, khi, klo, vthi, vtlo);
  } else {
    hipFuncSetAttribute(reinterpret_cast<const void*>(attn_fused<false>),
                        hipFuncAttributeMaxDynamicSharedMemorySize, LDS_BYTES);
    attn_fused<false><<<dim3(8192), NTHREADS, LDS_BYTES, stream>>>(
        q, k, v, m, out, w, khi, klo, vthi, vtlo);
  }
}